// Round 1
// baseline (1608.100 us; speedup 1.0000x reference)
//
#include <hip/hip_runtime.h>
#include <hip/hip_bf16.h>

#define DIN 96
#define DOUT 32
#define NH 4
#define DTOT 128          // NH * DOUT, also the concat output width
#define SLOPE 0.2f
#define NPB 16            // nodes per block in feat_kernel

// ---------------------------------------------------------------------------
// Kernel A: h[n][head*32+j] = x[n] @ W[head],  plus per-node attention scalars
//   alpha_s[n*NH+head] = h[n,head]·a[head,:32]
//   alpha_d[n*NH+head] = h[n,head]·a[head,32:]
// W (96x128 reshaped) staged in LDS, x tile staged in LDS.
// Thread map: node = t>>4 (16 nodes/block), col_base = (t&15)*8.
// ---------------------------------------------------------------------------
__global__ __launch_bounds__(256) void feat_kernel(
    const float* __restrict__ x, const float* __restrict__ W,
    const float* __restrict__ a,
    float* __restrict__ h, float* __restrict__ as_, float* __restrict__ ad_,
    int n_nodes)
{
    __shared__ float Wl[DIN * DTOT];      // 48 KiB: Wl[k*128 + head*32 + j]
    __shared__ float xs[NPB * DIN];       // 6 KiB
    __shared__ float al[NH * 2 * DOUT];   // 1 KiB
    const int t = threadIdx.x;

    for (int i = t; i < DIN * DTOT; i += 256) {
        int k = i >> 7, c = i & 127;
        int head = c >> 5, j = c & 31;
        Wl[i] = W[head * (DIN * DOUT) + k * DOUT + j];
    }
    for (int i = t; i < NH * 2 * DOUT; i += 256) al[i] = a[i];

    const int node0 = blockIdx.x * NPB;
    for (int i = t; i < NPB * DIN; i += 256) {
        int gidx = node0 * DIN + i;
        xs[i] = (gidx < n_nodes * DIN) ? x[gidx] : 0.f;
    }
    __syncthreads();

    const int node = t >> 4;
    const int cb = (t & 15) << 3;
    float acc[8];
#pragma unroll
    for (int j = 0; j < 8; ++j) acc[j] = 0.f;

#pragma unroll 4
    for (int k = 0; k < DIN; ++k) {
        float xv = xs[node * DIN + k];
#pragma unroll
        for (int j = 0; j < 8; ++j)
            acc[j] += xv * Wl[k * DTOT + cb + j];
    }

    const int g = node0 + node;
    if (g < n_nodes) {
        float4* hp = (float4*)&h[(size_t)g * DTOT + cb];
        hp[0] = make_float4(acc[0], acc[1], acc[2], acc[3]);
        hp[1] = make_float4(acc[4], acc[5], acc[6], acc[7]);
    }

    const int head = cb >> 5;
    const int j0 = cb & 31;
    float ps = 0.f, pd = 0.f;
#pragma unroll
    for (int j = 0; j < 8; ++j) {
        ps += acc[j] * al[head * 64 + j0 + j];
        pd += acc[j] * al[head * 64 + 32 + j0 + j];
    }
    // reduce across the 4 lanes (consecutive) sharing (node, head)
    ps += __shfl_xor(ps, 1); ps += __shfl_xor(ps, 2);
    pd += __shfl_xor(pd, 1); pd += __shfl_xor(pd, 2);
    if ((t & 3) == 0 && g < n_nodes) {
        as_[g * NH + head] = ps;
        ad_[g * NH + head] = pd;
    }
}

// ---------------------------------------------------------------------------
// Kernel B: per edge e, per col c (=head*32+j):
//   s  = alpha_s[src,head] + alpha_d[dst,head]
//   ee = exp(-leaky_relu(s))
//   atomicAdd(out[src*128+c], ee * h[dst*128+c])
// 2 edges per 256-thread block; wave reads h[dst] as 256B contiguous chunks.
// ---------------------------------------------------------------------------
__global__ __launch_bounds__(256) void edge_kernel(
    const int* __restrict__ esrc, const int* __restrict__ edst,
    const float* __restrict__ h,
    const float* __restrict__ as_, const float* __restrict__ ad_,
    float* __restrict__ acc, int n_edges)
{
    const int t = threadIdx.x;
    const int e = blockIdx.x * 2 + (t >> 7);
    if (e >= n_edges) return;
    const int c = t & 127;
    const int head = c >> 5;
    const int src = esrc[e];
    const int dst = edst[e];
    const float s = as_[src * NH + head] + ad_[dst * NH + head];
    const float lr = s > 0.f ? s : SLOPE * s;
    const float ee = __expf(-lr);
    const float val = ee * h[(size_t)dst * DTOT + c];
    atomicAdd(&acc[(size_t)src * DTOT + c], val);
}

// ---------------------------------------------------------------------------
// Kernel C: in-place ELU on the accumulated output.
// ---------------------------------------------------------------------------
__global__ __launch_bounds__(256) void elu_kernel(float* __restrict__ out, int n4)
{
    int i = blockIdx.x * 256 + threadIdx.x;
    if (i >= n4) return;
    float4 v = ((float4*)out)[i];
    v.x = v.x > 0.f ? v.x : __expf(v.x) - 1.f;
    v.y = v.y > 0.f ? v.y : __expf(v.y) - 1.f;
    v.z = v.z > 0.f ? v.z : __expf(v.z) - 1.f;
    v.w = v.w > 0.f ? v.w : __expf(v.w) - 1.f;
    ((float4*)out)[i] = v;
}

extern "C" void kernel_launch(void* const* d_in, const int* in_sizes, int n_in,
                              void* d_out, int out_size, void* d_ws, size_t ws_size,
                              hipStream_t stream)
{
    const float* x  = (const float*)d_in[0];
    const float* W  = (const float*)d_in[1];
    const float* a  = (const float*)d_in[2];
    const int* esrc = (const int*)d_in[3];
    const int* edst = (const int*)d_in[4];
    const int n_nodes = in_sizes[0] / DIN;
    const int n_edges = in_sizes[3];
    float* out = (float*)d_out;

    float* h   = (float*)d_ws;                          // [n_nodes * 128]
    float* as_ = h   + (size_t)n_nodes * DTOT;          // [n_nodes * 4]
    float* ad_ = as_ + (size_t)n_nodes * NH;            // [n_nodes * 4]

    hipMemsetAsync(d_out, 0, (size_t)out_size * sizeof(float), stream);

    feat_kernel<<<(n_nodes + NPB - 1) / NPB, 256, 0, stream>>>(
        x, W, a, h, as_, ad_, n_nodes);

    edge_kernel<<<(n_edges + 1) / 2, 256, 0, stream>>>(
        esrc, edst, h, as_, ad_, out, n_edges);

    elu_kernel<<<(out_size / 4 + 255) / 256, 256, 0, stream>>>(out, out_size / 4);
}

// Round 2
// 1205.451 us; speedup vs baseline: 1.3340x; 1.3340x over previous
//
#include <hip/hip_runtime.h>
#include <hip/hip_bf16.h>

#define DIN 96
#define DOUT 32
#define NH 4
#define DTOT 128          // NH * DOUT, also the concat output width
#define SLOPE 0.2f
#define NPB 16            // nodes per block in feat_kernel

// ---------------------------------------------------------------------------
// Kernel A: h[n][head*32+j] = x[n] @ W[head],  plus per-node attention scalars
// ---------------------------------------------------------------------------
__global__ __launch_bounds__(256) void feat_kernel(
    const float* __restrict__ x, const float* __restrict__ W,
    const float* __restrict__ a,
    float* __restrict__ h, float* __restrict__ as_, float* __restrict__ ad_,
    int n_nodes)
{
    __shared__ float Wl[DIN * DTOT];      // 48 KiB: Wl[k*128 + head*32 + j]
    __shared__ float xs[NPB * DIN];       // 6 KiB
    __shared__ float al[NH * 2 * DOUT];   // 1 KiB
    const int t = threadIdx.x;

    for (int i = t; i < DIN * DTOT; i += 256) {
        int k = i >> 7, c = i & 127;
        int head = c >> 5, j = c & 31;
        Wl[i] = W[head * (DIN * DOUT) + k * DOUT + j];
    }
    for (int i = t; i < NH * 2 * DOUT; i += 256) al[i] = a[i];

    const int node0 = blockIdx.x * NPB;
    for (int i = t; i < NPB * DIN; i += 256) {
        int gidx = node0 * DIN + i;
        xs[i] = (gidx < n_nodes * DIN) ? x[gidx] : 0.f;
    }
    __syncthreads();

    const int node = t >> 4;
    const int cb = (t & 15) << 3;
    float acc[8];
#pragma unroll
    for (int j = 0; j < 8; ++j) acc[j] = 0.f;

#pragma unroll 4
    for (int k = 0; k < DIN; ++k) {
        float xv = xs[node * DIN + k];
#pragma unroll
        for (int j = 0; j < 8; ++j)
            acc[j] += xv * Wl[k * DTOT + cb + j];
    }

    const int g = node0 + node;
    if (g < n_nodes) {
        float4* hp = (float4*)&h[(size_t)g * DTOT + cb];
        hp[0] = make_float4(acc[0], acc[1], acc[2], acc[3]);
        hp[1] = make_float4(acc[4], acc[5], acc[6], acc[7]);
    }

    const int head = cb >> 5;
    const int j0 = cb & 31;
    float ps = 0.f, pd = 0.f;
#pragma unroll
    for (int j = 0; j < 8; ++j) {
        ps += acc[j] * al[head * 64 + j0 + j];
        pd += acc[j] * al[head * 64 + 32 + j0 + j];
    }
    ps += __shfl_xor(ps, 1); ps += __shfl_xor(ps, 2);
    pd += __shfl_xor(pd, 1); pd += __shfl_xor(pd, 2);
    if ((t & 3) == 0 && g < n_nodes) {
        as_[g * NH + head] = ps;
        ad_[g * NH + head] = pd;
    }
}

// ---------------------------------------------------------------------------
// CSR build: histogram -> exclusive scan (3 kernels) -> bucket scatter
// ---------------------------------------------------------------------------
__global__ __launch_bounds__(256) void hist_kernel(
    const int* __restrict__ esrc, int* __restrict__ deg, int n_edges)
{
    int e = blockIdx.x * 256 + threadIdx.x;
    if (e < n_edges) atomicAdd(&deg[esrc[e]], 1);
}

// scan1: per-1024-chunk exclusive scan; chunk totals -> bsum
__global__ __launch_bounds__(256) void scan1_kernel(
    const int* __restrict__ deg, int* __restrict__ excl,
    int* __restrict__ bsum, int n)
{
    __shared__ int tmp[256];
    const int t = threadIdx.x;
    const int base = blockIdx.x * 1024;
    const int i0 = base + t * 4;
    int v[4]; int s = 0;
#pragma unroll
    for (int j = 0; j < 4; ++j) {
        v[j] = (i0 + j < n) ? deg[i0 + j] : 0;
        s += v[j];
    }
    tmp[t] = s;
    __syncthreads();
    for (int off = 1; off < 256; off <<= 1) {
        int xv = (t >= off) ? tmp[t - off] : 0;
        __syncthreads();
        tmp[t] += xv;
        __syncthreads();
    }
    int incl = tmp[t];
    if (t == 255) bsum[blockIdx.x] = incl;
    int run = incl - s;   // exclusive at thread start
#pragma unroll
    for (int j = 0; j < 4; ++j) {
        if (i0 + j < n) excl[i0 + j] = run;
        run += v[j];
    }
}

// scan2: exclusive scan of chunk totals (nb <= 1024), in place
__global__ __launch_bounds__(1024) void scan2_kernel(int* __restrict__ bsum, int nb)
{
    __shared__ int tmp[1024];
    const int t = threadIdx.x;
    int v = (t < nb) ? bsum[t] : 0;
    tmp[t] = v;
    __syncthreads();
    for (int off = 1; off < 1024; off <<= 1) {
        int xv = (t >= off) ? tmp[t - off] : 0;
        __syncthreads();
        tmp[t] += xv;
        __syncthreads();
    }
    if (t < nb) bsum[t] = tmp[t] - v;
}

// scan3: finalize offsets (+chunk base) and init cursor
__global__ __launch_bounds__(256) void scan3_kernel(
    int* __restrict__ excl, const int* __restrict__ bsum,
    int* __restrict__ cursor, int n)
{
    int i = blockIdx.x * 256 + threadIdx.x;
    if (i < n) {
        int o = excl[i] + bsum[i >> 10];
        excl[i] = o;
        cursor[i] = o;
    }
}

__global__ __launch_bounds__(256) void scatter_kernel(
    const int* __restrict__ esrc, const int* __restrict__ edst,
    int* __restrict__ cursor, int* __restrict__ slots, int n_edges)
{
    int e = blockIdx.x * 256 + threadIdx.x;
    if (e < n_edges) {
        int pos = atomicAdd(&cursor[esrc[e]], 1);
        slots[pos] = edst[e];
    }
}

// ---------------------------------------------------------------------------
// Gather: per node (128 threads), walk its edge bucket, accumulate in reg,
// fused ELU, single store. No atomics.
// ---------------------------------------------------------------------------
__global__ __launch_bounds__(256) void gather_kernel(
    const int* __restrict__ slots, const int* __restrict__ offsets,
    const int* __restrict__ deg,
    const float* __restrict__ h,
    const float* __restrict__ as_, const float* __restrict__ ad_,
    float* __restrict__ out, int n_nodes)
{
    const int t = threadIdx.x;
    const int node = blockIdx.x * 2 + (t >> 7);
    if (node >= n_nodes) return;
    const int c = t & 127;
    const int head = c >> 5;
    const float asv = as_[node * NH + head];
    const int beg = offsets[node];
    const int d = deg[node];
    float acc = 0.f;
    int dst = (d > 0) ? slots[beg] : 0;
    for (int k = 0; k < d; ++k) {
        int nxt = (k + 1 < d) ? slots[beg + k + 1] : 0;   // prefetch
        float s = asv + ad_[dst * NH + head];
        float lr = s > 0.f ? s : SLOPE * s;
        float ee = __expf(-lr);
        acc = fmaf(ee, h[(size_t)dst * DTOT + c], acc);
        dst = nxt;
    }
    out[(size_t)node * DTOT + c] = acc > 0.f ? acc : __expf(acc) - 1.f;
}

extern "C" void kernel_launch(void* const* d_in, const int* in_sizes, int n_in,
                              void* d_out, int out_size, void* d_ws, size_t ws_size,
                              hipStream_t stream)
{
    const float* x  = (const float*)d_in[0];
    const float* W  = (const float*)d_in[1];
    const float* a  = (const float*)d_in[2];
    const int* esrc = (const int*)d_in[3];
    const int* edst = (const int*)d_in[4];
    const int n_nodes = in_sizes[0] / DIN;
    const int n_edges = in_sizes[3];
    float* out = (float*)d_out;

    // workspace layout (all 16B-aligned: segment sizes are multiples of 4 elems)
    float* h    = (float*)d_ws;                           // [N*128]
    float* as_  = h   + (size_t)n_nodes * DTOT;           // [N*4]
    float* ad_  = as_ + (size_t)n_nodes * NH;             // [N*4]
    int*   deg  = (int*)(ad_ + (size_t)n_nodes * NH);     // [N]
    int*   offs = deg  + n_nodes;                         // [N]
    int*   curs = offs + n_nodes;                         // [N]
    int*   bsum = curs + n_nodes;                         // [1024]
    int*   slots = bsum + 1024;                           // [E]

    const int nchunk = (n_nodes + 1023) / 1024;

    hipMemsetAsync(deg, 0, (size_t)n_nodes * sizeof(int), stream);

    feat_kernel<<<(n_nodes + NPB - 1) / NPB, 256, 0, stream>>>(
        x, W, a, h, as_, ad_, n_nodes);

    hist_kernel<<<(n_edges + 255) / 256, 256, 0, stream>>>(esrc, deg, n_edges);
    scan1_kernel<<<nchunk, 256, 0, stream>>>(deg, offs, bsum, n_nodes);
    scan2_kernel<<<1, 1024, 0, stream>>>(bsum, nchunk);
    scan3_kernel<<<(n_nodes + 255) / 256, 256, 0, stream>>>(offs, bsum, curs, n_nodes);
    scatter_kernel<<<(n_edges + 255) / 256, 256, 0, stream>>>(
        esrc, edst, curs, slots, n_edges);

    gather_kernel<<<(n_nodes + 1) / 2, 256, 0, stream>>>(
        slots, offs, deg, h, as_, ad_, out, n_nodes);
}

// Round 3
// 869.969 us; speedup vs baseline: 1.8485x; 1.3856x over previous
//
#include <hip/hip_runtime.h>
#include <hip/hip_bf16.h>

#define DIN 96
#define DOUT 32
#define NH 4
#define DTOT 128          // NH * DOUT, also the concat output width
#define SLOPE 0.2f
#define NPB 16            // nodes per block in feat_kernel

// ---------------------------------------------------------------------------
// Kernel A: h[n] = x[n] @ W (all heads), plus per-node attention exp factors:
//   usrc[n*4+head] = (exp(-as), exp(-0.2*as)),  as = h[n,head]·a[head,:32]
//   vdst[n*4+head] = (exp(-ad), exp(-0.2*ad)),  ad = h[n,head]·a[head,32:]
// Then edge coefficient ee = exp(-leaky(as+ad)) = min(u.x*v.x, u.y*v.y).
// ---------------------------------------------------------------------------
__global__ __launch_bounds__(256) void feat_kernel(
    const float* __restrict__ x, const float* __restrict__ W,
    const float* __restrict__ a,
    float* __restrict__ h, float2* __restrict__ usrc, float2* __restrict__ vdst,
    int n_nodes)
{
    __shared__ float Wl[DIN * DTOT];      // 48 KiB: Wl[k*128 + head*32 + j]
    __shared__ float xs[NPB * DIN];       // 6 KiB
    __shared__ float al[NH * 2 * DOUT];   // 1 KiB
    const int t = threadIdx.x;

    for (int i = t; i < DIN * DTOT; i += 256) {
        int k = i >> 7, c = i & 127;
        int head = c >> 5, j = c & 31;
        Wl[i] = W[head * (DIN * DOUT) + k * DOUT + j];
    }
    for (int i = t; i < NH * 2 * DOUT; i += 256) al[i] = a[i];

    const int node0 = blockIdx.x * NPB;
    for (int i = t; i < NPB * DIN; i += 256) {
        int gidx = node0 * DIN + i;
        xs[i] = (gidx < n_nodes * DIN) ? x[gidx] : 0.f;
    }
    __syncthreads();

    const int node = t >> 4;
    const int cb = (t & 15) << 3;
    float acc[8];
#pragma unroll
    for (int j = 0; j < 8; ++j) acc[j] = 0.f;

#pragma unroll 4
    for (int k = 0; k < DIN; ++k) {
        float xv = xs[node * DIN + k];
#pragma unroll
        for (int j = 0; j < 8; ++j)
            acc[j] += xv * Wl[k * DTOT + cb + j];
    }

    const int g = node0 + node;
    if (g < n_nodes) {
        float4* hp = (float4*)&h[(size_t)g * DTOT + cb];
        hp[0] = make_float4(acc[0], acc[1], acc[2], acc[3]);
        hp[1] = make_float4(acc[4], acc[5], acc[6], acc[7]);
    }

    const int head = cb >> 5;
    const int j0 = cb & 31;
    float ps = 0.f, pd = 0.f;
#pragma unroll
    for (int j = 0; j < 8; ++j) {
        ps += acc[j] * al[head * 64 + j0 + j];
        pd += acc[j] * al[head * 64 + 32 + j0 + j];
    }
    ps += __shfl_xor(ps, 1); ps += __shfl_xor(ps, 2);
    pd += __shfl_xor(pd, 1); pd += __shfl_xor(pd, 2);
    if ((t & 3) == 0 && g < n_nodes) {
        usrc[g * NH + head] = make_float2(__expf(-ps), __expf(-SLOPE * ps));
        vdst[g * NH + head] = make_float2(__expf(-pd), __expf(-SLOPE * pd));
    }
}

// ---------------------------------------------------------------------------
// CSR build: histogram -> exclusive scan over PADDED degrees (buckets start
// 16B-aligned for int4 slot loads) -> bucket scatter
// ---------------------------------------------------------------------------
__global__ __launch_bounds__(256) void hist_kernel(
    const int* __restrict__ esrc, int* __restrict__ deg, int n_edges)
{
    int e = blockIdx.x * 256 + threadIdx.x;
    if (e < n_edges) atomicAdd(&deg[esrc[e]], 1);
}

__global__ __launch_bounds__(256) void scan1_kernel(
    const int* __restrict__ deg, int* __restrict__ excl,
    int* __restrict__ bsum, int n)
{
    __shared__ int tmp[256];
    const int t = threadIdx.x;
    const int base = blockIdx.x * 1024;
    const int i0 = base + t * 4;
    int v[4]; int s = 0;
#pragma unroll
    for (int j = 0; j < 4; ++j) {
        v[j] = (i0 + j < n) ? ((deg[i0 + j] + 3) & ~3) : 0;   // padded degree
        s += v[j];
    }
    tmp[t] = s;
    __syncthreads();
    for (int off = 1; off < 256; off <<= 1) {
        int xv = (t >= off) ? tmp[t - off] : 0;
        __syncthreads();
        tmp[t] += xv;
        __syncthreads();
    }
    int incl = tmp[t];
    if (t == 255) bsum[blockIdx.x] = incl;
    int run = incl - s;
#pragma unroll
    for (int j = 0; j < 4; ++j) {
        if (i0 + j < n) excl[i0 + j] = run;
        run += v[j];
    }
}

__global__ __launch_bounds__(1024) void scan2_kernel(int* __restrict__ bsum, int nb)
{
    __shared__ int tmp[1024];
    const int t = threadIdx.x;
    int v = (t < nb) ? bsum[t] : 0;
    tmp[t] = v;
    __syncthreads();
    for (int off = 1; off < 1024; off <<= 1) {
        int xv = (t >= off) ? tmp[t - off] : 0;
        __syncthreads();
        tmp[t] += xv;
        __syncthreads();
    }
    if (t < nb) bsum[t] = tmp[t] - v;
}

__global__ __launch_bounds__(256) void scan3_kernel(
    int* __restrict__ excl, const int* __restrict__ bsum,
    int* __restrict__ cursor, int n)
{
    int i = blockIdx.x * 256 + threadIdx.x;
    if (i < n) {
        int o = excl[i] + bsum[i >> 10];
        excl[i] = o;
        cursor[i] = o;
    }
}

__global__ __launch_bounds__(256) void scatter_kernel(
    const int* __restrict__ esrc, const int* __restrict__ edst,
    int* __restrict__ cursor, int* __restrict__ slots, int n_edges)
{
    int e = blockIdx.x * 256 + threadIdx.x;
    if (e < n_edges) {
        int pos = atomicAdd(&cursor[esrc[e]], 1);
        slots[pos] = edst[e];
    }
}

// ---------------------------------------------------------------------------
// Gather: 64 lanes per node, 2 cols per lane (float2 h loads). Edge loop
// unrolled x4 with 4 independent accumulators + pipelined int4 slot prefetch.
// ee = min(u.x*v.x, u.y*v.y). Fused ELU, single store, no atomics.
// ---------------------------------------------------------------------------
__global__ __launch_bounds__(256) void gather_kernel(
    const int* __restrict__ slots, const int* __restrict__ offsets,
    const int* __restrict__ deg,
    const float* __restrict__ h,
    const float2* __restrict__ usrc, const float2* __restrict__ vdst,
    float* __restrict__ out, int n_nodes)
{
    const int t = threadIdx.x;
    const int node = blockIdx.x * 4 + (t >> 6);
    if (node >= n_nodes) return;
    const int l = t & 63;          // lane within node group; cols {2l, 2l+1}
    const int head = l >> 4;
    const float2 u = usrc[node * NH + head];
    const int beg = offsets[node]; // multiple of 4
    const int d = deg[node];
    const float2* __restrict__ hv = (const float2*)h;   // [N*64]

    float2 a0 = {0.f, 0.f}, a1 = {0.f, 0.f}, a2 = {0.f, 0.f}, a3 = {0.f, 0.f};
    int k = 0;
    int4 dd = (d >= 4) ? *(const int4*)(slots + beg) : make_int4(0, 0, 0, 0);
    for (; k + 4 <= d; k += 4) {
        const int4 cur = dd;
        if (k + 8 <= d) dd = *(const int4*)(slots + beg + k + 4);
        float2 v0 = vdst[cur.x * NH + head];
        float2 v1 = vdst[cur.y * NH + head];
        float2 v2 = vdst[cur.z * NH + head];
        float2 v3 = vdst[cur.w * NH + head];
        float2 h0 = hv[(size_t)cur.x * 64 + l];
        float2 h1 = hv[(size_t)cur.y * 64 + l];
        float2 h2 = hv[(size_t)cur.z * 64 + l];
        float2 h3 = hv[(size_t)cur.w * 64 + l];
        float e0 = fminf(u.x * v0.x, u.y * v0.y);
        float e1 = fminf(u.x * v1.x, u.y * v1.y);
        float e2 = fminf(u.x * v2.x, u.y * v2.y);
        float e3 = fminf(u.x * v3.x, u.y * v3.y);
        a0.x = fmaf(e0, h0.x, a0.x); a0.y = fmaf(e0, h0.y, a0.y);
        a1.x = fmaf(e1, h1.x, a1.x); a1.y = fmaf(e1, h1.y, a1.y);
        a2.x = fmaf(e2, h2.x, a2.x); a2.y = fmaf(e2, h2.y, a2.y);
        a3.x = fmaf(e3, h3.x, a3.x); a3.y = fmaf(e3, h3.y, a3.y);
    }
    for (; k < d; ++k) {
        int dst = slots[beg + k];
        float2 v = vdst[dst * NH + head];
        float2 hx = hv[(size_t)dst * 64 + l];
        float e = fminf(u.x * v.x, u.y * v.y);
        a0.x = fmaf(e, hx.x, a0.x); a0.y = fmaf(e, hx.y, a0.y);
    }
    float rx = (a0.x + a1.x) + (a2.x + a3.x);
    float ry = (a0.y + a1.y) + (a2.y + a3.y);
    rx = rx > 0.f ? rx : __expf(rx) - 1.f;
    ry = ry > 0.f ? ry : __expf(ry) - 1.f;
    ((float2*)out)[(size_t)node * 64 + l] = make_float2(rx, ry);
}

extern "C" void kernel_launch(void* const* d_in, const int* in_sizes, int n_in,
                              void* d_out, int out_size, void* d_ws, size_t ws_size,
                              hipStream_t stream)
{
    const float* x  = (const float*)d_in[0];
    const float* W  = (const float*)d_in[1];
    const float* a  = (const float*)d_in[2];
    const int* esrc = (const int*)d_in[3];
    const int* edst = (const int*)d_in[4];
    const int n_nodes = in_sizes[0] / DIN;
    const int n_edges = in_sizes[3];
    float* out = (float*)d_out;

    float*  h    = (float*)d_ws;                           // [N*128]
    float2* usrc = (float2*)(h + (size_t)n_nodes * DTOT);  // [N*4]
    float2* vdst = usrc + (size_t)n_nodes * NH;            // [N*4]
    int*    deg  = (int*)(vdst + (size_t)n_nodes * NH);    // [N]
    int*    offs = deg  + n_nodes;                         // [N]
    int*    curs = offs + n_nodes;                         // [N]
    int*    bsum = curs + n_nodes;                         // [1024]
    int*    slots = bsum + 1024;                           // [E + 3N] (padded buckets)

    const int nchunk = (n_nodes + 1023) / 1024;

    hipMemsetAsync(deg, 0, (size_t)n_nodes * sizeof(int), stream);

    feat_kernel<<<(n_nodes + NPB - 1) / NPB, 256, 0, stream>>>(
        x, W, a, h, usrc, vdst, n_nodes);

    hist_kernel<<<(n_edges + 255) / 256, 256, 0, stream>>>(esrc, deg, n_edges);
    scan1_kernel<<<nchunk, 256, 0, stream>>>(deg, offs, bsum, n_nodes);
    scan2_kernel<<<1, 1024, 0, stream>>>(bsum, nchunk);
    scan3_kernel<<<(n_nodes + 255) / 256, 256, 0, stream>>>(offs, bsum, curs, n_nodes);
    scatter_kernel<<<(n_edges + 255) / 256, 256, 0, stream>>>(
        esrc, edst, curs, slots, n_edges);

    gather_kernel<<<(n_nodes + 3) / 4, 256, 0, stream>>>(
        slots, offs, deg, h, usrc, vdst, out, n_nodes);
}

// Round 4
// 499.466 us; speedup vs baseline: 3.2196x; 1.7418x over previous
//
#include <hip/hip_runtime.h>
#include <hip/hip_bf16.h>

#define DIN 96
#define DOUT 32
#define NH 4
#define DTOT 128          // NH * DOUT, concat output width
#define SLOPE 0.2f
#define NPB 16            // nodes per block in feat_kernel
#define BSH 7             // bucket shift: 128 src nodes per bucket
#define BNODES 128
#define MAXB 1024         // max buckets (N <= 131072)
#define EPB 16384         // edges per block in bin kernels

// pack two fp32 -> two bf16 (RNE) in one uint
__device__ __forceinline__ unsigned int packbf2(float lo, float hi) {
    unsigned int a = __float_as_uint(lo), b = __float_as_uint(hi);
    a += 0x7fffu + ((a >> 16) & 1u);
    b += 0x7fffu + ((b >> 16) & 1u);
    return (a >> 16) | (b & 0xffff0000u);
}

// ---------------------------------------------------------------------------
// Kernel A: h[n] = x[n] @ W (all heads) stored as packed bf16, plus per-node
// attention exp factors:
//   usrc[n*4+head] = (exp(-as), exp(-0.2*as)),  as = h[n,head]·a[head,:32]
//   vdst[n*4+head] = (exp(-ad), exp(-0.2*ad))
// Edge coefficient ee = exp(-leaky(as+ad)) = min(u.x*v.x, u.y*v.y).
// ---------------------------------------------------------------------------
__global__ __launch_bounds__(256) void feat_kernel(
    const float* __restrict__ x, const float* __restrict__ W,
    const float* __restrict__ a,
    unsigned int* __restrict__ hq,      // [N*64] packed bf16 pairs
    float2* __restrict__ usrc, float2* __restrict__ vdst,
    int n_nodes)
{
    __shared__ float Wl[DIN * DTOT];
    __shared__ float xs[NPB * DIN];
    __shared__ float al[NH * 2 * DOUT];
    const int t = threadIdx.x;

    for (int i = t; i < DIN * DTOT; i += 256) {
        int k = i >> 7, c = i & 127;
        int head = c >> 5, j = c & 31;
        Wl[i] = W[head * (DIN * DOUT) + k * DOUT + j];
    }
    for (int i = t; i < NH * 2 * DOUT; i += 256) al[i] = a[i];

    const int node0 = blockIdx.x * NPB;
    for (int i = t; i < NPB * DIN; i += 256) {
        int gidx = node0 * DIN + i;
        xs[i] = (gidx < n_nodes * DIN) ? x[gidx] : 0.f;
    }
    __syncthreads();

    const int node = t >> 4;
    const int cb = (t & 15) << 3;
    float acc[8];
#pragma unroll
    for (int j = 0; j < 8; ++j) acc[j] = 0.f;

#pragma unroll 4
    for (int k = 0; k < DIN; ++k) {
        float xv = xs[node * DIN + k];
#pragma unroll
        for (int j = 0; j < 8; ++j)
            acc[j] += xv * Wl[k * DTOT + cb + j];
    }

    const int g = node0 + node;
    if (g < n_nodes) {
        uint4 pk;
        pk.x = packbf2(acc[0], acc[1]);
        pk.y = packbf2(acc[2], acc[3]);
        pk.z = packbf2(acc[4], acc[5]);
        pk.w = packbf2(acc[6], acc[7]);
        *(uint4*)&hq[(size_t)g * 64 + (cb >> 1)] = pk;
    }

    const int head = cb >> 5;
    const int j0 = cb & 31;
    float ps = 0.f, pd = 0.f;
#pragma unroll
    for (int j = 0; j < 8; ++j) {
        ps += acc[j] * al[head * 64 + j0 + j];
        pd += acc[j] * al[head * 64 + 32 + j0 + j];
    }
    ps += __shfl_xor(ps, 1); ps += __shfl_xor(ps, 2);
    pd += __shfl_xor(pd, 1); pd += __shfl_xor(pd, 2);
    if ((t & 3) == 0 && g < n_nodes) {
        usrc[g * NH + head] = make_float2(__expf(-ps), __expf(-SLOPE * ps));
        vdst[g * NH + head] = make_float2(__expf(-pd), __expf(-SLOPE * pd));
    }
}

// ---------------------------------------------------------------------------
// Two-level counting sort of edges by src.
// Level 1: coarse buckets of 128 src nodes. Level 2: per-bucket LDS sort.
// ---------------------------------------------------------------------------

// count edges per coarse bucket (LDS hist, one global atomic per block-bucket)
__global__ __launch_bounds__(256) void bincount_kernel(
    const int* __restrict__ esrc, int* __restrict__ counts, int n_edges, int nb)
{
    __shared__ int bc[MAXB];
    const int t = threadIdx.x;
    for (int i = t; i < nb; i += 256) bc[i] = 0;
    __syncthreads();
    const int base = blockIdx.x * EPB;
    const int end = min(base + EPB, n_edges);
    for (int e = base + t; e < end; e += 256)
        atomicAdd(&bc[esrc[e] >> BSH], 1);
    __syncthreads();
    for (int i = t; i < nb; i += 256)
        if (bc[i] > 0) atomicAdd(&counts[i], bc[i]);
}

// scan buckets: bbase (binned layout), gcur (reservation cursor),
// sbase (4-aligned slots layout with +512 pad slack per bucket)
__global__ __launch_bounds__(1024) void bscan_kernel(
    const int* __restrict__ counts, int* __restrict__ bbase,
    int* __restrict__ gcur, int* __restrict__ sbase, int nb)
{
    __shared__ int tmp[1024];
    const int t = threadIdx.x;
    int v = (t < nb) ? counts[t] : 0;
    tmp[t] = v;
    __syncthreads();
    for (int off = 1; off < 1024; off <<= 1) {
        int xv = (t >= off) ? tmp[t - off] : 0;
        __syncthreads();
        tmp[t] += xv;
        __syncthreads();
    }
    if (t < nb) {
        int excl = tmp[t] - v;
        bbase[t] = excl;
        gcur[t] = excl;
        sbase[t] = ((excl + 3) & ~3) + t * (4 * BNODES);
    }
}

// scatter edges (packed srcl|dst) into coarse bucket regions
__global__ __launch_bounds__(256) void binscatter_kernel(
    const int* __restrict__ esrc, const int* __restrict__ edst,
    int* __restrict__ gcur, unsigned int* __restrict__ binned,
    int n_edges, int nb)
{
    __shared__ int bc[MAXB];
    const int t = threadIdx.x;
    for (int i = t; i < nb; i += 256) bc[i] = 0;
    __syncthreads();
    const int base = blockIdx.x * EPB;
    const int end = min(base + EPB, n_edges);
    for (int e = base + t; e < end; e += 256)
        atomicAdd(&bc[esrc[e] >> BSH], 1);
    __syncthreads();
    // reserve a run per non-empty bucket; bc becomes the running cursor
    for (int i = t; i < nb; i += 256) {
        int c = bc[i];
        bc[i] = (c > 0) ? atomicAdd(&gcur[i], c) : 0;
    }
    __syncthreads();
    for (int e = base + t; e < end; e += 256) {
        int s = esrc[e];
        int pos = atomicAdd(&bc[s >> BSH], 1);
        binned[pos] = ((unsigned int)(s & (BNODES - 1)) << 17) | (unsigned int)edst[e];
    }
}

// per-bucket fine sort: LDS per-node hist + scan, write offs/deg and slots
__global__ __launch_bounds__(256) void binfine_kernel(
    const unsigned int* __restrict__ binned,
    const int* __restrict__ counts, const int* __restrict__ bbase,
    const int* __restrict__ sbase,
    int* __restrict__ offs, int* __restrict__ deg,
    int* __restrict__ slots, int n_nodes)
{
    __shared__ int dcnt[BNODES];
    __shared__ int sc[BNODES];
    __shared__ int dcur[BNODES];
    const int t = threadIdx.x;
    const int b = blockIdx.x;
    const int cnt = counts[b];
    const int start = bbase[b];
    const int sb = sbase[b];
    const int node0 = b << BSH;

    if (t < BNODES) dcnt[t] = 0;
    __syncthreads();
    for (int i = t; i < cnt; i += 256)
        atomicAdd(&dcnt[binned[start + i] >> 17], 1);
    __syncthreads();
    int pd = 0;
    if (t < BNODES) { pd = (dcnt[t] + 3) & ~3; sc[t] = pd; }
    __syncthreads();
    for (int off = 1; off < BNODES; off <<= 1) {
        int v = 0;
        if (t < BNODES && t >= off) v = sc[t - off];
        __syncthreads();
        if (t < BNODES) sc[t] += v;
        __syncthreads();
    }
    if (t < BNODES) {
        int o = sb + sc[t] - pd;   // 4-aligned per-node start
        dcur[t] = o;
        int node = node0 + t;
        if (node < n_nodes) { offs[node] = o; deg[node] = dcnt[t]; }
    }
    __syncthreads();
    for (int i = t; i < cnt; i += 256) {
        unsigned int w = binned[start + i];
        int pos = atomicAdd(&dcur[w >> 17], 1);
        slots[pos] = (int)(w & 0x1ffffu);
    }
}

// ---------------------------------------------------------------------------
// Gather: 64 lanes per node, 2 cols per lane (bf16x2 h loads). Edge loop
// unrolled x4, pipelined int4 slot prefetch, fused ELU, no atomics.
// ---------------------------------------------------------------------------
__global__ __launch_bounds__(256) void gather_kernel(
    const int* __restrict__ slots, const int* __restrict__ offsets,
    const int* __restrict__ deg,
    const unsigned int* __restrict__ hv,    // [N*64] packed bf16 pairs
    const float2* __restrict__ usrc, const float2* __restrict__ vdst,
    float* __restrict__ out, int n_nodes)
{
    const int t = threadIdx.x;
    const int node = blockIdx.x * 4 + (t >> 6);
    if (node >= n_nodes) return;
    const int l = t & 63;          // cols {2l, 2l+1}
    const int head = l >> 4;
    const float2 u = usrc[node * NH + head];
    const int beg = offsets[node]; // multiple of 4
    const int d = deg[node];

    float ax0 = 0.f, ay0 = 0.f, ax1 = 0.f, ay1 = 0.f;
    float ax2 = 0.f, ay2 = 0.f, ax3 = 0.f, ay3 = 0.f;
    int k = 0;
    int4 dd = (d >= 4) ? *(const int4*)(slots + beg) : make_int4(0, 0, 0, 0);
    for (; k + 4 <= d; k += 4) {
        const int4 cur = dd;
        if (k + 8 <= d) dd = *(const int4*)(slots + beg + k + 4);
        float2 v0 = vdst[cur.x * NH + head];
        float2 v1 = vdst[cur.y * NH + head];
        float2 v2 = vdst[cur.z * NH + head];
        float2 v3 = vdst[cur.w * NH + head];
        unsigned int w0 = hv[(size_t)cur.x * 64 + l];
        unsigned int w1 = hv[(size_t)cur.y * 64 + l];
        unsigned int w2 = hv[(size_t)cur.z * 64 + l];
        unsigned int w3 = hv[(size_t)cur.w * 64 + l];
        float e0 = fminf(u.x * v0.x, u.y * v0.y);
        float e1 = fminf(u.x * v1.x, u.y * v1.y);
        float e2 = fminf(u.x * v2.x, u.y * v2.y);
        float e3 = fminf(u.x * v3.x, u.y * v3.y);
        ax0 = fmaf(e0, __uint_as_float(w0 << 16), ax0);
        ay0 = fmaf(e0, __uint_as_float(w0 & 0xffff0000u), ay0);
        ax1 = fmaf(e1, __uint_as_float(w1 << 16), ax1);
        ay1 = fmaf(e1, __uint_as_float(w1 & 0xffff0000u), ay1);
        ax2 = fmaf(e2, __uint_as_float(w2 << 16), ax2);
        ay2 = fmaf(e2, __uint_as_float(w2 & 0xffff0000u), ay2);
        ax3 = fmaf(e3, __uint_as_float(w3 << 16), ax3);
        ay3 = fmaf(e3, __uint_as_float(w3 & 0xffff0000u), ay3);
    }
    for (; k < d; ++k) {
        int dst = slots[beg + k];
        float2 v = vdst[dst * NH + head];
        unsigned int w = hv[(size_t)dst * 64 + l];
        float e = fminf(u.x * v.x, u.y * v.y);
        ax0 = fmaf(e, __uint_as_float(w << 16), ax0);
        ay0 = fmaf(e, __uint_as_float(w & 0xffff0000u), ay0);
    }
    float rx = (ax0 + ax1) + (ax2 + ax3);
    float ry = (ay0 + ay1) + (ay2 + ay3);
    rx = rx > 0.f ? rx : __expf(rx) - 1.f;
    ry = ry > 0.f ? ry : __expf(ry) - 1.f;
    ((float2*)out)[(size_t)node * 64 + l] = make_float2(rx, ry);
}

extern "C" void kernel_launch(void* const* d_in, const int* in_sizes, int n_in,
                              void* d_out, int out_size, void* d_ws, size_t ws_size,
                              hipStream_t stream)
{
    const float* x  = (const float*)d_in[0];
    const float* W  = (const float*)d_in[1];
    const float* a  = (const float*)d_in[2];
    const int* esrc = (const int*)d_in[3];
    const int* edst = (const int*)d_in[4];
    const int n_nodes = in_sizes[0] / DIN;
    const int n_edges = in_sizes[3];
    float* out = (float*)d_out;

    const int nb = (n_nodes + BNODES - 1) >> BSH;

    // workspace layout
    unsigned int* hq = (unsigned int*)d_ws;                 // [N*64] bf16 pairs, 25.6MB
    float2* usrc = (float2*)(hq + (size_t)n_nodes * 64);    // [N*4]
    float2* vdst = usrc + (size_t)n_nodes * NH;             // [N*4]
    int* offs   = (int*)(vdst + (size_t)n_nodes * NH);      // [N]
    int* deg    = offs + n_nodes;                           // [N]
    int* counts = deg + n_nodes;                            // [MAXB]
    int* bbase  = counts + MAXB;                            // [MAXB]
    int* gcur   = bbase + MAXB;                             // [MAXB]
    int* sbase  = gcur + MAXB;                              // [MAXB]
    unsigned int* binned = (unsigned int*)(sbase + MAXB);   // [E]
    int* slots  = (int*)(binned + n_edges);                 // [E + 512*nb + 64]

    hipMemsetAsync(counts, 0, MAXB * sizeof(int), stream);

    feat_kernel<<<(n_nodes + NPB - 1) / NPB, 256, 0, stream>>>(
        x, W, a, hq, usrc, vdst, n_nodes);

    const int binblocks = (n_edges + EPB - 1) / EPB;
    bincount_kernel<<<binblocks, 256, 0, stream>>>(esrc, counts, n_edges, nb);
    bscan_kernel<<<1, 1024, 0, stream>>>(counts, bbase, gcur, sbase, nb);
    binscatter_kernel<<<binblocks, 256, 0, stream>>>(
        esrc, edst, gcur, binned, n_edges, nb);
    binfine_kernel<<<nb, 256, 0, stream>>>(
        binned, counts, bbase, sbase, offs, deg, slots, n_nodes);

    gather_kernel<<<(n_nodes + 3) / 4, 256, 0, stream>>>(
        slots, offs, deg, hq, usrc, vdst, out, n_nodes);
}